// Round 14
// baseline (74.013 us; speedup 1.0000x reference)
//
#include <hip/hip_runtime.h>

// dist[pix, o] = ||x[pix]||^2 + ||omega[o]||^2 - 2 * x.omega
// M = 262144 pixels, O = 256 protos, D = 64.
// Round-14: EXACT round-13 structure (32x32x16 MFMA, A=x rows / B=omega cols,
// scalar dword stores with 32-lane contiguous runs = full 128B line requests,
// omega frags in LDS). Single change: x loads PLAIN instead of nontemporal.
// Theory: the 32x32 A-layout makes x loads 16 isolated 16B requests per row
// (adjacent lanes are different 256B-apart rows); nt no-allocate loads fetch
// each 64B granule ~4x from HBM (268MB vs 67MB). Plain loads let L1 capture
// the line on first touch; the wave's remaining requests for that row hit L1.
// R6's plain-load regression was coupled to 64B partial-line stores (dirty
// merge eviction); R13's full-line store requests remove that coupling.

typedef __attribute__((ext_vector_type(4))) float f32x4;
typedef __attribute__((ext_vector_type(16))) float f32x16;
typedef __attribute__((ext_vector_type(8))) short s16x8;
typedef __attribute__((ext_vector_type(4))) unsigned int u32x4;

constexpr int D_ = 64;
constexpr int O_ = 256;
constexpr int M_ = 16 * 128 * 128;              // 262144
constexpr int ITERS = 2;
constexpr int PIX_PER_BLOCK = 4 * 32 * ITERS;   // 256
constexpr int NBLOCKS = M_ / PIX_PER_BLOCK;     // 1024

__device__ __forceinline__ unsigned short f2bf(float f) {
    // round-to-nearest-even fp32 -> bf16
    unsigned u = __builtin_bit_cast(unsigned, f);
    u += 0x7FFFu + ((u >> 16) & 1u);
    return (unsigned short)(u >> 16);
}

__global__ __launch_bounds__(256, 4) void dist_kernel(
    const float* __restrict__ x,
    const float* __restrict__ om,
    float* __restrict__ out)
{
    // [ (T*4+s)*64 + lane ]: 16B bf16 B-fragment of proto-tile T (32 protos),
    // k-step s. Lane (o=lane&31, h=lane>>5) holds omega[T*32+o][s*16+h*8 ..+8).
    __shared__ u32x4 lfrag[32 * 64];          // 32 KiB
    __shared__ __align__(16) float lp2[O_];   // 1 KiB

    const int tid  = threadIdx.x;
    const int wave = tid >> 6;
    const int lane = tid & 63;
    const int p    = lane & 31;   // A: pixel row ; B: proto col ; store col
    const int h    = lane >> 5;   // k-half

    // ---------- once per block: omega -> bf16 fragments + p2 ---------------
#pragma unroll
    for (int tt = 0; tt < 2; ++tt) {
        const int T = wave * 2 + tt;
        float p2p = 0.f;
#pragma unroll
        for (int s = 0; s < 4; ++s) {
            const float* src = om + (T * 32 + p) * D_ + s * 16 + h * 8;
            f32x4 v0 = *(const f32x4*)(src);
            f32x4 v1 = *(const f32x4*)(src + 4);
            s16x8 f;
#pragma unroll
            for (int j = 0; j < 4; ++j) {
                f[j]     = (short)f2bf(v0[j]); p2p += v0[j] * v0[j];
                f[4 + j] = (short)f2bf(v1[j]); p2p += v1[j] * v1[j];
            }
            lfrag[(T * 4 + s) * 64 + lane] = __builtin_bit_cast(u32x4, f);
        }
        p2p += __shfl_xor(p2p, 32);           // join the two k-halves
        if (lane < 32) lp2[T * 32 + p] = p2p;
    }
    __syncthreads();

    float p2r[8];
#pragma unroll
    for (int T = 0; T < 8; ++T) p2r[T] = lp2[T * 32 + p];  // 2-way bcast, free

    // ---------- steady state: 32 pixels per wave per iteration --------------
    const int pix0 = blockIdx.x * PIX_PER_BLOCK;

    for (int it = 0; it < ITERS; ++it) {
        const int rbase = pix0 + it * 128 + wave * 32;

        // A-frag: lane (p,h) holds x[rbase+p][s*16 + h*8 ..+8) for s=0..3
        const float* xs = x + (size_t)(rbase + p) * D_ + h * 8;
        s16x8 Af[4];
        float x2p = 0.f;
#pragma unroll
        for (int s = 0; s < 4; ++s) {
            f32x4 a0 = *(const f32x4*)(xs + s * 16);       // PLAIN load
            f32x4 a1 = *(const f32x4*)(xs + s * 16 + 4);   // PLAIN load
#pragma unroll
            for (int j = 0; j < 4; ++j) {
                Af[s][j]     = (short)f2bf(a0[j]); x2p += a0[j] * a0[j];
                Af[s][4 + j] = (short)f2bf(a1[j]); x2p += a1[j] * a1[j];
            }
        }
        x2p += __shfl_xor(x2p, 32);           // full ||x||^2 of pixel p

        // x2 for the 16 C-rows this lane will store: row = (reg&3)+8*(reg>>2)+4h
        float x2r[16];
#pragma unroll
        for (int reg = 0; reg < 16; ++reg)
            x2r[reg] = __shfl(x2p, (reg & 3) + 8 * (reg >> 2) + 4 * h);

        // base: row offset 4h baked in; col = p
        float* const obase = out + (size_t)(rbase + 4 * h) * O_ + p;

#pragma unroll
        for (int T = 0; T < 8; ++T) {
            f32x16 acc = {0.f, 0.f, 0.f, 0.f, 0.f, 0.f, 0.f, 0.f,
                          0.f, 0.f, 0.f, 0.f, 0.f, 0.f, 0.f, 0.f};
#pragma unroll
            for (int s = 0; s < 4; ++s) {
                s16x8 Bf = __builtin_bit_cast(s16x8, lfrag[(T * 4 + s) * 64 + lane]);
                acc = __builtin_amdgcn_mfma_f32_32x32x16_bf16(Af[s], Bf, acc, 0, 0, 0);
            }
            // epilogue + store: scalar dword, lanes 0..31 = protos T*32..+31
            // contiguous -> two full 128B line requests per instruction
#pragma unroll
            for (int reg = 0; reg < 16; ++reg) {
                const float val = (x2r[reg] + p2r[T]) - 2.f * acc[reg];
                obase[((reg & 3) + 8 * (reg >> 2)) * O_ + T * 32] = val;
            }
        }
    }
}

extern "C" void kernel_launch(void* const* d_in, const int* in_sizes, int n_in,
                              void* d_out, int out_size, void* d_ws, size_t ws_size,
                              hipStream_t stream) {
    const float* x  = (const float*)d_in[0];   // [16,128,128,64] fp32
    const float* om = (const float*)d_in[1];   // [256,64] fp32
    float* out = (float*)d_out;                // [16,128,128,256,1] fp32

    dist_kernel<<<dim3(NBLOCKS), dim3(256), 0, stream>>>(x, om, out);
}